// Round 29
// baseline (93.779 us; speedup 1.0000x reference)
//
#include <hip/hip_runtime.h>
#include <math.h>

#define IMG_W 512
#define IMG_H 512
#define RPT 8
#define STRIPS (IMG_H / RPT)     // 64 strips per image
#define IMG_PX (IMG_H * IMG_W)   // 262144
#define NBLOCKS 2048

// exp(-10*z) = exp2(-14.4269504*z)
#define NEG10_LOG2E (-14.426950408889634f)

// Guaranteed single v_exp_f32 (args are always <= 0 here)
__device__ __forceinline__ float exp2_raw(float x) {
    float r;
    asm("v_exp_f32 %0, %1" : "=v"(r) : "v"(x));
    return r;
}

// ---- float2 packed helpers ----
__device__ __forceinline__ float2 mk2(float a, float b) { float2 r; r.x = a; r.y = b; return r; }
__device__ __forceinline__ float2 add2(float2 a, float2 b) { return mk2(a.x + b.x, a.y + b.y); }
__device__ __forceinline__ float2 sub2(float2 a, float2 b) { return mk2(a.x - b.x, a.y - b.y); }
__device__ __forceinline__ float2 fma2c(float k, float2 a, float2 b) {
    return mk2(fmaf(k, a.x, b.x), fmaf(k, a.y, b.y));
}

// Per-row factorized taps for 2 pixels, packed. d=R-L, s=L+C+R, t=s+C.
// sobel_x = d_a + 2 d_b + d_c ; sobel_y = t_c - t_a ; lap = 9(t_b-s_b) - (s_a+s_b+s_c)
struct Rw { float2 d, t, s; };

__device__ __forceinline__ Rw make_dst(float4 v, bool eL, bool eR) {
    v.x = eL ? 0.f : v.x;              // in-place keeps v[0:3] adjacency
    v.w = eR ? 0.f : v.w;
    const float2 A = mk2(v.x, v.y);
    const float2 B = mk2(v.z, v.w);
    const float2 M = mk2(v.y, v.z);    // C-pair (straddle)
    Rw w;
    w.d = sub2(B, A);
    w.s = add2(add2(A, B), M);
    w.t = add2(w.s, M);
    return w;
}

__device__ __forceinline__ Rw zero_dst() {
    Rw w; w.d = mk2(0.f, 0.f); w.t = mk2(0.f, 0.f); w.s = mk2(0.f, 0.f); return w;
}

// 512-thread blocks (8 waves); charbonnier(x) ~= |x| for x>=0 (verified absmax 0.0156 < 0.0258).
// Single launch: last-done block reduces the 2048 partials (deterministic fixed-order sum).
__global__ __launch_bounds__(512, 4) void loss_partial_kernel(
        const float* __restrict__ pred, const float* __restrict__ targ,
        float* __restrict__ partial, unsigned int* __restrict__ counter,
        float* __restrict__ out, int nimg, float scale) {
    const int tid  = blockIdx.x * 512 + threadIdx.x;
    const int g    = tid & 255;                  // x-group (2 px)
    const int rest = tid >> 8;
    const int strip = rest & (STRIPS - 1);
    const int b     = rest >> 6;                 // / STRIPS
    const int x0    = g << 1;                    // 0..510
    const int y0    = strip * RPT;
    const bool eL = (x0 == 0);
    const bool eR = (x0 == IMG_W - 2);
    const int nmax = nimg * IMG_PX - 4;          // last safe dwordx4 start
    const bool lastStrip = (strip == STRIPS - 1);

    // flat element index of (b, y0, x0-1); rows step by IMG_W
    const int rowIdx = b * IMG_PX + y0 * IMG_W + (x0 - 1);

    // window rows a=(y0-1), b=(y0)
    Rw pa, pb, ta, tb;
    if (strip == 0) {                 // y0-1 == -1 -> zero row, no load
        pa = zero_dst(); ta = zero_dst();
    } else {
        pa = make_dst(*(const float4*)(pred + rowIdx - IMG_W), eL, eR);
        ta = make_dst(*(const float4*)(targ + rowIdx - IMG_W), eL, eR);
    }
    {
        const int ic = max(rowIdx, 0);           // only b=0,strip=0,x0=0 hits -1 (2 px, ~1e-8 effect)
        pb = make_dst(*(const float4*)(pred + ic), eL, eR);
        tb = make_dst(*(const float4*)(targ + ic), eL, eR);
    }

    // raw quads for row y0+1 (always a valid row: y0+1 <= 505)
    float4 rp = *(const float4*)(pred + rowIdx + IMG_W);
    float4 rt = *(const float4*)(targ + rowIdx + IMG_W);

    float sXY = 0.f, sL = 0.f;
#pragma unroll
    for (int i = 0; i < RPT; ++i) {
        float4 rp2, rt2;
        if (i < RPT - 1) {
            const int ip = min(rowIdx + (i + 2) * IMG_W, nmax);  // clamp for strip 63
            rp2 = *(const float4*)(pred + ip);
            rt2 = *(const float4*)(targ + ip);
        }

        Rw pc, tc;
        if (i == RPT - 1 && lastStrip) {
            pc = zero_dst(); tc = zero_dst();
        } else {
            pc = make_dst(rp, eL, eR);
            tc = make_dst(rt, eL, eR);
        }

        const float2 sxp = add2(fma2c(2.f, pb.d, pa.d), pc.d);
        const float2 syp = sub2(pc.t, pa.t);
        const float2 nsp = add2(add2(pa.s, pb.s), pc.s);
        const float2 lpp = fma2c(9.f, sub2(pb.t, pb.s), mk2(-nsp.x, -nsp.y));

        const float2 sxt = add2(fma2c(2.f, tb.d, ta.d), tc.d);
        const float2 syt = sub2(tc.t, ta.t);
        const float2 nst = add2(add2(ta.s, tb.s), tc.s);
        const float2 lpt = fma2c(9.f, sub2(tb.t, tb.s), mk2(-nst.x, -nst.y));

        {   // pixel 0
            const float ax = fabsf(sxp.x) * exp2_raw(fabsf(sxt.x) * NEG10_LOG2E);
            const float ay = fabsf(syp.x) * exp2_raw(fabsf(syt.x) * NEG10_LOG2E);
            const float al = fabsf(lpp.x) * exp2_raw(fabsf(lpt.x) * NEG10_LOG2E);
            sXY += ax + ay;
            sL  += al;
        }
        {   // pixel 1
            const float ax = fabsf(sxp.y) * exp2_raw(fabsf(sxt.y) * NEG10_LOG2E);
            const float ay = fabsf(syp.y) * exp2_raw(fabsf(syt.y) * NEG10_LOG2E);
            const float al = fabsf(lpp.y) * exp2_raw(fabsf(lpt.y) * NEG10_LOG2E);
            sXY += ax + ay;
            sL  += al;
        }

        pa = pb; pb = pc;
        ta = tb; tb = tc;
        rp = rp2; rt = rt2;
    }

    float sum = fmaf(10.f, sXY, sL);

    // wave reduce, block reduce, publish partial
#pragma unroll
    for (int off = 32; off > 0; off >>= 1) sum += __shfl_down(sum, off, 64);
    __shared__ float ws[8];
    __shared__ unsigned int sticket;
    const int lane = threadIdx.x & 63, wid = threadIdx.x >> 6;
    if (lane == 0) ws[wid] = sum;
    __syncthreads();
    if (threadIdx.x == 0) {
        float t = 0.f;
#pragma unroll
        for (int j = 0; j < 8; ++j) t += ws[j];
        partial[blockIdx.x] = t;
        __threadfence();                         // make partial visible device-wide (release)
        sticket = atomicAdd(counter, 1u);        // device-scope ticket
    }
    __syncthreads();

    // last-done block reduces all partials (fixed index order -> deterministic)
    if (sticket == NBLOCKS - 1) {
        __threadfence();                         // acquire: see all partials
        float s = 0.f;
#pragma unroll
        for (int k = 0; k < NBLOCKS / 512; ++k)  // 4 per thread
            s += partial[threadIdx.x + k * 512];
#pragma unroll
        for (int off = 32; off > 0; off >>= 1) s += __shfl_down(s, off, 64);
        if (lane == 0) ws[wid] = s;
        __syncthreads();
        if (threadIdx.x == 0) {
            float t = 0.f;
#pragma unroll
            for (int j = 0; j < 8; ++j) t += ws[j];
            out[0] = t * scale;
        }
    }
}

extern "C" void kernel_launch(void* const* d_in, const int* in_sizes, int n_in,
                              void* d_out, int out_size, void* d_ws, size_t ws_size,
                              hipStream_t stream) {
    const float* pred = (const float*)d_in[0];
    const float* targ = (const float*)d_in[1];
    float* out = (float*)d_out;
    float* partial = (float*)d_ws;
    unsigned int* counter = (unsigned int*)((char*)d_ws + NBLOCKS * sizeof(float));

    const int total = in_sizes[0];                 // 64*512*512
    const int B = total / (IMG_H * IMG_W);         // 64
    const float scale = 1.0f / (float)total;

    hipMemsetAsync(counter, 0, sizeof(unsigned int), stream);
    loss_partial_kernel<<<NBLOCKS, 512, 0, stream>>>(pred, targ, partial, counter, out, B, scale);
}

// Round 30
// 31.794 us; speedup vs baseline: 2.9496x; 2.9496x over previous
//
#include <hip/hip_runtime.h>
#include <math.h>

#define IMG_W 512
#define IMG_H 512
#define RPT 8
#define STRIPS (IMG_H / RPT)     // 64 strips per image
#define IMG_PX (IMG_H * IMG_W)   // 262144

// exp(-10*z) = exp2(-14.4269504*z)
#define NEG10_LOG2E (-14.426950408889634f)

// Guaranteed single v_exp_f32 (args are always <= 0 here)
__device__ __forceinline__ float exp2_raw(float x) {
    float r;
    asm("v_exp_f32 %0, %1" : "=v"(r) : "v"(x));
    return r;
}

// ---- float2 packed helpers (compiler lowers to v_pk_{add,fma}_f32 on gfx950) ----
__device__ __forceinline__ float2 mk2(float a, float b) { float2 r; r.x = a; r.y = b; return r; }
__device__ __forceinline__ float2 add2(float2 a, float2 b) { return mk2(a.x + b.x, a.y + b.y); }
__device__ __forceinline__ float2 sub2(float2 a, float2 b) { return mk2(a.x - b.x, a.y - b.y); }
__device__ __forceinline__ float2 fma2c(float k, float2 a, float2 b) {
    return mk2(fmaf(k, a.x, b.x), fmaf(k, a.y, b.y));
}

// Per-row factorized taps for 2 pixels, packed. d=R-L, s=L+C+R, t=s+C.
// sobel_x = d_a + 2 d_b + d_c ; sobel_y = t_c - t_a ; lap = 9(t_b-s_b) - (s_a+s_b+s_c)
struct Rw { float2 d, t, s; };

// Aligned-pair formulation: A=(v0,v1), B=(v2,v3) are natural VGPR pairs after the
// in-place edge cndmasks; only M=(v1,v2) needs marshaling.
__device__ __forceinline__ Rw make_dst(float4 v, bool eL, bool eR) {
    v.x = eL ? 0.f : v.x;              // in-place keeps v[0:3] adjacency
    v.w = eR ? 0.f : v.w;
    const float2 A = mk2(v.x, v.y);
    const float2 B = mk2(v.z, v.w);
    const float2 M = mk2(v.y, v.z);    // C-pair (straddle)
    Rw w;
    w.d = sub2(B, A);                  // (v2-v0, v3-v1)
    w.s = add2(add2(A, B), M);         // (v0+v1+v2, v1+v2+v3)
    w.t = add2(w.s, M);
    return w;
}

__device__ __forceinline__ Rw zero_dst() {
    Rw w; w.d = mk2(0.f, 0.f); w.t = mk2(0.f, 0.f); w.s = mk2(0.f, 0.f); return w;
}

// 512-thread blocks (8 waves); charbonnier(x) ~= |x| for x>=0 (verified absmax 0.0156 < 0.0258)
__global__ __launch_bounds__(512, 4) void loss_partial_kernel(
        const float* __restrict__ pred, const float* __restrict__ targ,
        float* __restrict__ partial, int nimg) {
    const int tid  = blockIdx.x * 512 + threadIdx.x;
    const int g    = tid & 255;                  // x-group (2 px)
    const int rest = tid >> 8;
    const int strip = rest & (STRIPS - 1);
    const int b     = rest >> 6;                 // / STRIPS
    const int x0    = g << 1;                    // 0..510
    const int y0    = strip * RPT;
    const bool eL = (x0 == 0);
    const bool eR = (x0 == IMG_W - 2);
    const int nmax = nimg * IMG_PX - 4;          // last safe dwordx4 start
    const bool lastStrip = (strip == STRIPS - 1);

    // flat element index of (b, y0, x0-1); rows step by IMG_W
    const int rowIdx = b * IMG_PX + y0 * IMG_W + (x0 - 1);

    // window rows a=(y0-1), b=(y0)
    Rw pa, pb, ta, tb;
    if (strip == 0) {                 // y0-1 == -1 -> zero row, no load
        pa = zero_dst(); ta = zero_dst();
    } else {
        pa = make_dst(*(const float4*)(pred + rowIdx - IMG_W), eL, eR);
        ta = make_dst(*(const float4*)(targ + rowIdx - IMG_W), eL, eR);
    }
    {
        const int ic = max(rowIdx, 0);           // only b=0,strip=0,x0=0 hits -1 (2 px, ~1e-8 effect)
        pb = make_dst(*(const float4*)(pred + ic), eL, eR);
        tb = make_dst(*(const float4*)(targ + ic), eL, eR);
    }

    // raw quads for row y0+1 (always a valid row: y0+1 <= 505)
    float4 rp = *(const float4*)(pred + rowIdx + IMG_W);
    float4 rt = *(const float4*)(targ + rowIdx + IMG_W);

    float sXY = 0.f, sL = 0.f;
#pragma unroll
    for (int i = 0; i < RPT; ++i) {
        // prefetch raw quads for row y0+i+2 (skip on last iter: never consumed)
        float4 rp2, rt2;
        if (i < RPT - 1) {
            const int ip = min(rowIdx + (i + 2) * IMG_W, nmax);  // clamp for strip 63
            rp2 = *(const float4*)(pred + ip);
            rt2 = *(const float4*)(targ + ip);
        }

        // convert raw row y0+i+1 -> window row c (zero if beyond image: last iter of strip 63)
        Rw pc, tc;
        if (i == RPT - 1 && lastStrip) {
            pc = zero_dst(); tc = zero_dst();
        } else {
            pc = make_dst(rp, eL, eR);
            tc = make_dst(rt, eL, eR);
        }

        // packed stencils (both pixels at once)
        const float2 sxp = add2(fma2c(2.f, pb.d, pa.d), pc.d);
        const float2 syp = sub2(pc.t, pa.t);
        const float2 nsp = add2(add2(pa.s, pb.s), pc.s);
        const float2 lpp = fma2c(9.f, sub2(pb.t, pb.s), mk2(-nsp.x, -nsp.y));

        const float2 sxt = add2(fma2c(2.f, tb.d, ta.d), tc.d);
        const float2 syt = sub2(tc.t, ta.t);
        const float2 nst = add2(add2(ta.s, tb.s), tc.s);
        const float2 lpt = fma2c(9.f, sub2(tb.t, tb.s), mk2(-nst.x, -nst.y));

        // scalar tail per pixel: abs folds into VOP3 input modifiers; exp = raw v_exp_f32
        {   // pixel 0
            const float ax = fabsf(sxp.x) * exp2_raw(fabsf(sxt.x) * NEG10_LOG2E);
            const float ay = fabsf(syp.x) * exp2_raw(fabsf(syt.x) * NEG10_LOG2E);
            const float al = fabsf(lpp.x) * exp2_raw(fabsf(lpt.x) * NEG10_LOG2E);
            sXY += ax + ay;
            sL  += al;
        }
        {   // pixel 1
            const float ax = fabsf(sxp.y) * exp2_raw(fabsf(sxt.y) * NEG10_LOG2E);
            const float ay = fabsf(syp.y) * exp2_raw(fabsf(syt.y) * NEG10_LOG2E);
            const float al = fabsf(lpp.y) * exp2_raw(fabsf(lpt.y) * NEG10_LOG2E);
            sXY += ax + ay;
            sL  += al;
        }

        pa = pb; pb = pc;      // full unroll -> register renaming
        ta = tb; tb = tc;
        rp = rp2; rt = rt2;
    }

    float sum = fmaf(10.f, sXY, sL);

    // wave (64-lane) reduce, then 8-wave block reduce
#pragma unroll
    for (int off = 32; off > 0; off >>= 1) sum += __shfl_down(sum, off, 64);
    __shared__ float ws[8];
    const int lane = threadIdx.x & 63, wid = threadIdx.x >> 6;
    if (lane == 0) ws[wid] = sum;
    __syncthreads();
    if (threadIdx.x == 0) {
        float t = 0.f;
#pragma unroll
        for (int j = 0; j < 8; ++j) t += ws[j];
        partial[blockIdx.x] = t;
    }
}

__global__ __launch_bounds__(256) void loss_final_kernel(
        const float* __restrict__ partial, int n, float* __restrict__ out, float scale) {
    float s = 0.f;
    for (int i = threadIdx.x; i < n; i += 256) s += partial[i];
#pragma unroll
    for (int off = 32; off > 0; off >>= 1) s += __shfl_down(s, off, 64);
    __shared__ float ws[4];
    const int lane = threadIdx.x & 63, wid = threadIdx.x >> 6;
    if (lane == 0) ws[wid] = s;
    __syncthreads();
    if (threadIdx.x == 0) out[0] = (ws[0] + ws[1] + ws[2] + ws[3]) * scale;
}

extern "C" void kernel_launch(void* const* d_in, const int* in_sizes, int n_in,
                              void* d_out, int out_size, void* d_ws, size_t ws_size,
                              hipStream_t stream) {
    const float* pred = (const float*)d_in[0];
    const float* targ = (const float*)d_in[1];
    float* out = (float*)d_out;
    float* partial = (float*)d_ws;

    const int total = in_sizes[0];                 // 64*512*512
    const int B = total / (IMG_H * IMG_W);         // 64
    const int nblocks = (B * STRIPS * 256) / 512;  // 2048 blocks of 512 threads

    loss_partial_kernel<<<nblocks, 512, 0, stream>>>(pred, targ, partial, B);
    const float scale = 1.0f / (float)total;
    loss_final_kernel<<<1, 256, 0, stream>>>(partial, nblocks, out, scale);
}